// Round 3
// baseline (2371.913 us; speedup 1.0000x reference)
//
#include <hip/hip_runtime.h>
#include <math.h>

namespace {
constexpr int kB = 2;
constexpr int kN = 1024;
constexpr int kM = 16384;
constexpr float kSqrt3 = 1.7320508075688772f;

// workspace layout in floats
constexpr size_t A_OFF = 0;                              // [B,N,N] A; lower->Schur/L, upper->mirror L^T
constexpr size_t D_OFF = A_OFF + (size_t)kB * kN * kN;   // [B,8,128,128] inv of diag blocks
constexpr size_t Z_OFF = D_OFF + (size_t)kB * 8 * 128 * 128;   // [B,N] z = L^-1 (y-mean)
constexpr size_t K_OFF = Z_OFF + (size_t)kB * kN;        // per-wg w slabs [B*256][1024][64]
constexpr size_t WS_FLOATS = K_OFF + (size_t)kB * kN * kM;
}  // namespace

__device__ __forceinline__ float pair_kernel(
    float x0, float x1, float a1, float b1, float c1,
    float y0, float y1, float a2, float b2, float c2, float scale) {
  float det1 = a1 * b1 - c1 * c1;
  float det2 = a2 * b2 - c2 * c2;
  float s00 = a1 + a2, s11 = b1 + b2, s01 = c1 + c2;
  float sdet = s00 * s11 - s01 * s01;
  float d0 = x0 - y0, d1 = x1 - y1;
  float Q = 0.5f * (s11 * d0 * d0 - 2.0f * s01 * d0 * d1 + s00 * d1 * d1) / sdet;
  float C = 2.0f * sqrtf(sqrtf(det1)) * sqrtf(sqrtf(det2)) * rsqrtf(fmaxf(sdet, 1e-5f));
  float t = kSqrt3 * sqrtf(fmaxf(Q, 1e-5f));
  return (1.0f + t) * __expf(-t) * C * scale;
}

// ---------------- A = K_nn + diag(var) ----------------
__global__ __launch_bounds__(256) void build_A(
    const float* __restrict__ xt, const float* __restrict__ pt,
    const float* __restrict__ var, const float* __restrict__ sp,
    float* __restrict__ A) {
  int idx = blockIdx.x * 256 + threadIdx.x;  // B*N*N
  int b = idx / (kN * kN);
  int r = (idx / kN) % kN;
  int c = idx % kN;
  float scale = __expf(sp[0]);
  const float* x1 = xt + ((size_t)b * kN + r) * 2;
  const float* p1 = pt + ((size_t)b * kN + r) * 3;
  const float* x2 = xt + ((size_t)b * kN + c) * 2;
  const float* p2 = pt + ((size_t)b * kN + c) * 3;
  float k = pair_kernel(x1[0], x1[1], p1[0], p1[1], p1[2],
                        x2[0], x2[1], p2[0], p2[1], p2[2], scale);
  if (r == c) k += var[b * kN + r];
  A[(size_t)idx] = k;
}

// Lt swizzled indexers for chol_panel
__device__ __forceinline__ int lt_idx4(int row, int f4) {
  return row * 128 + ((f4 ^ ((row >> 2) & 7)) << 2);
}
__device__ __forceinline__ int lt_idx(int row, int col) {
  return row * 128 + ((((col >> 2) ^ ((row >> 2) & 7)) << 2) | (col & 3));
}

// ---------------- Cholesky panel factor (128x128) + explicit inverse ----------------
__global__ __launch_bounds__(1024) void chol_panel(float* __restrict__ A,
                                                   float* __restrict__ Dg, int p) {
  __shared__ float Lt[128 * 128];
  __shared__ float Dt[128 * 132];
  __shared__ float Tt[3 * 32 * 33];
  int b = blockIdx.x;
  int t = threadIdx.x;
  float* Ab = A + (size_t)b * kN * kN;
  int r0 = p * 128;
  int tx = t & 31, ty = t >> 5;
  int i0 = ty * 4, j0 = tx * 4;
  bool lower = (ty >= tx);
  float acc[4][4];
  if (lower) {
#pragma unroll
    for (int q = 0; q < 4; ++q) {
      float4 v = *(const float4*)&Ab[(size_t)(r0 + i0 + q) * kN + r0 + j0];
      acc[q][0] = v.x; acc[q][1] = v.y; acc[q][2] = v.z; acc[q][3] = v.w;
    }
  }
  for (int kb = 0; kb < 32; ++kb) {
    int K0 = kb * 4;
    if (ty == kb && tx == kb) {
#pragma unroll
      for (int c = 0; c < 4; ++c) {
        float d = sqrtf(acc[c][c]);
        float inv = 1.0f / d;
        acc[c][c] = d;
#pragma unroll
        for (int i = c + 1; i < 4; ++i) acc[i][c] *= inv;
#pragma unroll
        for (int j = c + 1; j < 4; ++j)
#pragma unroll
          for (int i = j; i < 4; ++i) acc[i][j] -= acc[i][c] * acc[j][c];
      }
#pragma unroll
      for (int q = 0; q < 4; ++q) {
        float4 v;
        v.x = acc[q][0];
        v.y = (q >= 1) ? acc[q][1] : 0.0f;
        v.z = (q >= 2) ? acc[q][2] : 0.0f;
        v.w = (q >= 3) ? acc[q][3] : 0.0f;
        *(float4*)&Lt[lt_idx4(K0 + q, kb)] = v;
      }
    }
    __syncthreads();
    if (tx == kb && ty > kb) {
      float L4[4][4];
#pragma unroll
      for (int c = 0; c < 4; ++c)
#pragma unroll
        for (int j = 0; j <= c; ++j) L4[c][j] = Lt[lt_idx(K0 + c, K0 + j)];
#pragma unroll
      for (int c = 0; c < 4; ++c) {
#pragma unroll
        for (int j = 0; j < c; ++j) {
          float m = L4[c][j];
#pragma unroll
          for (int q = 0; q < 4; ++q) acc[q][c] -= m * acc[q][j];
        }
        float inv = 1.0f / L4[c][c];
#pragma unroll
        for (int q = 0; q < 4; ++q) acc[q][c] *= inv;
      }
#pragma unroll
      for (int q = 0; q < 4; ++q) {
        float4 v = {acc[q][0], acc[q][1], acc[q][2], acc[q][3]};
        *(float4*)&Lt[lt_idx4(i0 + q, kb)] = v;
      }
    }
    __syncthreads();
    if (tx > kb && lower) {
      float4 Ri[4], Rj[4];
#pragma unroll
      for (int q = 0; q < 4; ++q) Ri[q] = *(const float4*)&Lt[lt_idx4(i0 + q, kb)];
#pragma unroll
      for (int q = 0; q < 4; ++q) Rj[q] = *(const float4*)&Lt[lt_idx4(j0 + q, kb)];
#pragma unroll
      for (int qr = 0; qr < 4; ++qr)
#pragma unroll
        for (int qc = 0; qc < 4; ++qc)
          acc[qr][qc] -= Ri[qr].x * Rj[qc].x + Ri[qr].y * Rj[qc].y +
                         Ri[qr].z * Rj[qc].z + Ri[qr].w * Rj[qc].w;
    }
  }
  if (t < 128) {
    int q = t >> 5, c = t & 31, base = q * 32;
    for (int r = 0; r < 32; ++r) {
      float x;
      if (r < c) x = 0.0f;
      else if (r == c) x = 1.0f / Lt[lt_idx(base + r, base + r)];
      else {
        float s = 0.0f;
        for (int j = c; j < r; ++j)
          s += Lt[lt_idx(base + r, base + j)] * Dt[(base + j) * 132 + base + c];
        x = -s / Lt[lt_idx(base + r, base + r)];
      }
      Dt[(base + r) * 132 + base + c] = x;
    }
  }
  __syncthreads();
  {
    int r = t >> 5, cl = t & 31;
    for (int s = 1; s <= 3; ++s) {
      for (int blk = 0; blk < 4 - s; ++blk) {
        int J = blk, I = J + s;
        float sum = 0.0f;
        for (int K = J; K < I; ++K)
          for (int j = 0; j < 32; ++j)
            sum += Lt[lt_idx(I * 32 + r, K * 32 + j)] * Dt[(K * 32 + j) * 132 + J * 32 + cl];
        Tt[blk * (32 * 33) + r * 33 + cl] = sum;
      }
      __syncthreads();
      for (int blk = 0; blk < 4 - s; ++blk) {
        int J = blk, I = J + s;
        float sum = 0.0f;
        for (int j = 0; j < 32; ++j)
          sum += Dt[(I * 32 + r) * 132 + I * 32 + j] * Tt[blk * (32 * 33) + j * 33 + cl];
        Dt[(I * 32 + r) * 132 + J * 32 + cl] = -sum;
      }
      __syncthreads();
    }
  }
#pragma unroll
  for (int q = 0; q < 4; ++q) {
    int j = t + 1024 * q;
    int r = j >> 5, ch = j & 31;
    float4 v = *(const float4*)&Lt[lt_idx4(r, ch)];
    int c0 = ch * 4;
    v.x = (c0 + 0 <= r) ? v.x : 0.0f;
    v.y = (c0 + 1 <= r) ? v.y : 0.0f;
    v.z = (c0 + 2 <= r) ? v.z : 0.0f;
    v.w = (c0 + 3 <= r) ? v.w : 0.0f;
    *(float4*)&Ab[(size_t)(r0 + r) * kN + r0 + c0] = v;
  }
  float* Db = Dg + (size_t)(b * 8 + p) * 16384;
#pragma unroll
  for (int q = 0; q < 4; ++q) {
    int j = t + 1024 * q;
    int r = j >> 5, ch = j & 31;
    float4 v = *(const float4*)&Dt[r * 132 + ch * 4];
    int c0 = ch * 4;
    v.x = (c0 + 0 <= r) ? v.x : 0.0f;
    v.y = (c0 + 1 <= r) ? v.y : 0.0f;
    v.z = (c0 + 2 <= r) ? v.z : 0.0f;
    v.w = (c0 + 3 <= r) ? v.w : 0.0f;
    *(float4*)&Db[r * 128 + c0] = v;
  }
}

// ---------------- fused trailing update: Li=A_ip*D^T (redundant), A_ij -= Li*Lj^T ----
// diag pairs (bi==bj) also write L_ip TRANSPOSED into the upper mirror block (p,i).
// dynamic LDS: 2 * 128*129 floats.
__global__ __launch_bounds__(1024) void chol_trail(float* __restrict__ A,
                                                   const float* __restrict__ Dg, int p) {
  extern __shared__ float sh[];
  float* buf0 = sh;
  float* buf1 = sh + 128 * 129;
  int b = blockIdx.y;
  int pid = blockIdx.x;
  int bi = 0;
  while ((bi + 1) * (bi + 2) / 2 <= pid) ++bi;
  int bj = pid - bi * (bi + 1) / 2;
  int i = p + 1 + bi, j = p + 1 + bj;
  float* Ab = A + (size_t)b * kN * kN;
  const float* Db = Dg + (size_t)(b * 8 + p) * 16384;
  int t = threadIdx.x;
  int tx = t & 31, ty = t >> 5;
  // stage A_ip -> buf0, D -> buf1
#pragma unroll
  for (int q = 0; q < 4; ++q) {
    int idx = t + 1024 * q;
    int r = idx >> 5, c4 = idx & 31;
    *(float4*)&buf0[r * 129 + c4 * 4] =
        *(const float4*)&Ab[(size_t)(i * 128 + r) * kN + p * 128 + c4 * 4];
    *(float4*)&buf1[r * 129 + c4 * 4] = *(const float4*)&Db[r * 128 + c4 * 4];
  }
  __syncthreads();
  float li[4][4] = {};
#pragma unroll 4
  for (int c = 0; c < 128; ++c) {
    float a[4], d[4];
#pragma unroll
    for (int q = 0; q < 4; ++q) a[q] = buf0[(ty * 4 + q) * 129 + c];
#pragma unroll
    for (int q = 0; q < 4; ++q) d[q] = buf1[(tx * 4 + q) * 129 + c];
#pragma unroll
    for (int qr = 0; qr < 4; ++qr)
#pragma unroll
      for (int qc = 0; qc < 4; ++qc) li[qr][qc] = fmaf(a[qr], d[qc], li[qr][qc]);
  }
  float lj[4][4];
  if (bi != bj) {
    __syncthreads();
#pragma unroll
    for (int q = 0; q < 4; ++q) {
      int idx = t + 1024 * q;
      int r = idx >> 5, c4 = idx & 31;
      *(float4*)&buf0[r * 129 + c4 * 4] =
          *(const float4*)&Ab[(size_t)(j * 128 + r) * kN + p * 128 + c4 * 4];
    }
    __syncthreads();
#pragma unroll
    for (int qr = 0; qr < 4; ++qr)
#pragma unroll
      for (int qc = 0; qc < 4; ++qc) lj[qr][qc] = 0.0f;
#pragma unroll 4
    for (int c = 0; c < 128; ++c) {
      float a[4], d[4];
#pragma unroll
      for (int q = 0; q < 4; ++q) a[q] = buf0[(ty * 4 + q) * 129 + c];
#pragma unroll
      for (int q = 0; q < 4; ++q) d[q] = buf1[(tx * 4 + q) * 129 + c];
#pragma unroll
      for (int qr = 0; qr < 4; ++qr)
#pragma unroll
        for (int qc = 0; qc < 4; ++qc) lj[qr][qc] = fmaf(a[qr], d[qc], lj[qr][qc]);
    }
  } else {
#pragma unroll
    for (int qr = 0; qr < 4; ++qr)
#pragma unroll
      for (int qc = 0; qc < 4; ++qc) lj[qr][qc] = li[qr][qc];
  }
  __syncthreads();
  // Li -> buf0, Lj -> buf1 ; diag wg writes mirror L_ip^T at block (p,i)
#pragma unroll
  for (int qr = 0; qr < 4; ++qr)
#pragma unroll
    for (int qc = 0; qc < 4; ++qc) {
      buf0[(ty * 4 + qr) * 129 + tx * 4 + qc] = li[qr][qc];
      buf1[(ty * 4 + qr) * 129 + tx * 4 + qc] = lj[qr][qc];
    }
  if (bi == bj) {
#pragma unroll
    for (int qr = 0; qr < 4; ++qr)
#pragma unroll
      for (int qc = 0; qc < 4; ++qc)
        Ab[(size_t)(p * 128 + tx * 4 + qc) * kN + i * 128 + ty * 4 + qr] = li[qr][qc];
  }
  __syncthreads();
  float s[4][4] = {};
#pragma unroll 4
  for (int m = 0; m < 128; ++m) {
    float a[4], d[4];
#pragma unroll
    for (int q = 0; q < 4; ++q) a[q] = buf0[(ty * 4 + q) * 129 + m];
#pragma unroll
    for (int q = 0; q < 4; ++q) d[q] = buf1[(tx * 4 + q) * 129 + m];
#pragma unroll
    for (int qr = 0; qr < 4; ++qr)
#pragma unroll
      for (int qc = 0; qc < 4; ++qc) s[qr][qc] = fmaf(a[qr], d[qc], s[qr][qc]);
  }
#pragma unroll
  for (int qr = 0; qr < 4; ++qr) {
    float* dst = &Ab[(size_t)(i * 128 + ty * 4 + qr) * kN + j * 128 + tx * 4];
    float4 v = *(const float4*)dst;
    v.x -= s[qr][0]; v.y -= s[qr][1]; v.z -= s[qr][2]; v.w -= s[qr][3];
    *(float4*)dst = v;
  }
}

// ---------------- z = L^-1 (y - mean), nlml (reads mirror for off-diag L) --------
__global__ __launch_bounds__(128) void solve_small(
    const float* __restrict__ A, const float* __restrict__ Dg,
    const float* __restrict__ y, const float* __restrict__ meanp,
    float* __restrict__ zbuf, float* __restrict__ out) {
  __shared__ __align__(16) float zs[1024];
  __shared__ float ts[128];
  __shared__ float red[128];
  int b = blockIdx.x, t = threadIdx.x;
  const float* Ab = A + (size_t)b * kN * kN;
  float mv = meanp[b];
  for (int q = t; q < 1024; q += 128) zs[q] = y[b * kN + q] - mv;
  __syncthreads();
  for (int i = 0; i < 8; ++i) {
    float acc = zs[i * 128 + t];
    for (int k = 0; k < i; ++k) {
      const float* Lik = Ab + (size_t)(k * 128) * kN + i * 128 + t;  // mirror: L_ik[t][c]
      for (int c = 0; c < 128; ++c) acc -= Lik[(size_t)c * kN] * zs[k * 128 + c];
    }
    ts[t] = acc;
    __syncthreads();
    const float* Db = Dg + (size_t)(b * 8 + i) * 16384 + t * 128;
    float zv = 0.0f;
    for (int c = 0; c <= t; ++c) zv += Db[c] * ts[c];
    zs[i * 128 + t] = zv;
    __syncthreads();
  }
  float df = 0.0f, ld = 0.0f;
  for (int q = t; q < 1024; q += 128) {
    df += zs[q] * zs[q];
    ld += logf(Ab[(size_t)q * kN + q]);
  }
  red[t] = df;
  __syncthreads();
  for (int s = 64; s > 0; s >>= 1) {
    if (t < s) red[t] += red[t + s];
    __syncthreads();
  }
  float dfs = red[0];
  __syncthreads();
  red[t] = ld;
  __syncthreads();
  for (int s = 64; s > 0; s >>= 1) {
    if (t < s) red[t] += red[t + s];
    __syncthreads();
  }
  if (t == 0)
    out[2 * kB * kM + b] = 0.5f * dfs + red[0] + 0.5f * 1024.0f * logf(6.283185307179586f);
  for (int q = t; q < 1024; q += 128) zbuf[b * kN + q] = zs[q];
}

// ---------------- fused: build K tiles + w = L^-1 K (recurrence) + pred outputs ----
// grid (kM/64, kB), 256 threads. Per-wg private slab [1024][64] in Kw scratch.
__global__ __launch_bounds__(256) void fused_solve(
    const float* __restrict__ A, const float* __restrict__ Dg,
    const float* __restrict__ xt, const float* __restrict__ pt,
    const float* __restrict__ xs, const float* __restrict__ ps,
    const float* __restrict__ sp, const float* __restrict__ meanp,
    const float* __restrict__ zbuf, float* __restrict__ Kw,
    float* __restrict__ out) {
  __shared__ float As[32 * 132];   // staged A-operand chunk (col-major [c][r]); reused as reduce buf
  __shared__ float Bs[32 * 68];    // staged w_k chunk [c][m]; reused as train-pt buf
  __shared__ float Ts[128 * 68];   // T = K_i - sum L_ik w_k, [c][m]
  __shared__ float zs[128];
  __shared__ float tss[64 * 5];    // test points (x0,x1,a,b,c)
  int mt = blockIdx.x, b = blockIdx.y;
  int t = threadIdx.x;
  int tx = t & 15, ty = t >> 4;    // tx: m (4 each), ty: rows (8 each)
  const float* Lm = A + (size_t)b * kN * kN;
  float* slab = Kw + ((size_t)(b * 256 + mt)) * (1024 * 64);
  float scale = __expf(sp[0]);
  if (t < 64) {
    int mg = mt * 64 + t;
    tss[t * 5 + 0] = xs[((size_t)b * kM + mg) * 2 + 0];
    tss[t * 5 + 1] = xs[((size_t)b * kM + mg) * 2 + 1];
    tss[t * 5 + 2] = ps[((size_t)b * kM + mg) * 3 + 0];
    tss[t * 5 + 3] = ps[((size_t)b * kM + mg) * 3 + 1];
    tss[t * 5 + 4] = ps[((size_t)b * kM + mg) * 3 + 2];
  }
  float pmc[4] = {}, s2c[4] = {};
  for (int i = 0; i < 8; ++i) {
    // ---- load train points for block i (alias Bs) + z slice ----
    if (t < 128) {
      int n = i * 128 + t;
      Bs[t * 5 + 0] = xt[((size_t)b * kN + n) * 2 + 0];
      Bs[t * 5 + 1] = xt[((size_t)b * kN + n) * 2 + 1];
      Bs[t * 5 + 2] = pt[((size_t)b * kN + n) * 3 + 0];
      Bs[t * 5 + 3] = pt[((size_t)b * kN + n) * 3 + 1];
      Bs[t * 5 + 4] = pt[((size_t)b * kN + n) * 3 + 2];
      zs[t] = zbuf[b * kN + n];
    }
    __syncthreads();
    // ---- K build into acc ----
    float acc[8][4];
#pragma unroll
    for (int q = 0; q < 8; ++q) {
      int r = ty * 8 + q;
      float X0 = Bs[r * 5 + 0], X1 = Bs[r * 5 + 1];
      float A1 = Bs[r * 5 + 2], B1 = Bs[r * 5 + 3], C1 = Bs[r * 5 + 4];
#pragma unroll
      for (int jj = 0; jj < 4; ++jj) {
        const float* tp = &tss[(tx * 4 + jj) * 5];
        acc[q][jj] = pair_kernel(X0, X1, A1, B1, C1, tp[0], tp[1], tp[2], tp[3], tp[4], scale);
      }
    }
    __syncthreads();
    // ---- subtract sum_{k<i} L_ik w_k ----
    for (int k = 0; k < i; ++k) {
      const float* wk = slab + (size_t)(k * 128) * 64;
      for (int kc = 0; kc < 128; kc += 32) {
#pragma unroll
        for (int q = 0; q < 4; ++q) {
          int idx = t + 256 * q;
          int c = idx >> 5, r4 = idx & 31;
          // mirror: L_ik[r][kc+c] at A[(k*128+kc+c)*kN + i*128 + r]
          float4 v = *(const float4*)&Lm[(size_t)(k * 128 + kc + c) * kN + i * 128 + r4 * 4];
          *(float4*)&As[c * 132 + r4 * 4] = v;
        }
#pragma unroll
        for (int q = 0; q < 2; ++q) {
          int idx = t + 256 * q;
          int c = idx >> 4, m4 = idx & 15;
          float4 v = *(const float4*)&wk[(size_t)(kc + c) * 64 + m4 * 4];
          *(float4*)&Bs[c * 68 + m4 * 4] = v;
        }
        __syncthreads();
#pragma unroll 4
        for (int c = 0; c < 32; ++c) {
          float4 a0 = *(const float4*)&As[c * 132 + ty * 8];
          float4 a1 = *(const float4*)&As[c * 132 + ty * 8 + 4];
          float4 bv = *(const float4*)&Bs[c * 68 + tx * 4];
          float av[8] = {a0.x, a0.y, a0.z, a0.w, a1.x, a1.y, a1.z, a1.w};
          float bb[4] = {bv.x, bv.y, bv.z, bv.w};
#pragma unroll
          for (int q = 0; q < 8; ++q)
#pragma unroll
            for (int jj = 0; jj < 4; ++jj) acc[q][jj] = fmaf(-av[q], bb[jj], acc[q][jj]);
        }
        __syncthreads();
      }
    }
    // ---- w_i = D_i * T ----
#pragma unroll
    for (int q = 0; q < 8; ++q) {
      float4 v = {acc[q][0], acc[q][1], acc[q][2], acc[q][3]};
      *(float4*)&Ts[(ty * 8 + q) * 68 + tx * 4] = v;
    }
    __syncthreads();
#pragma unroll
    for (int q = 0; q < 8; ++q)
#pragma unroll
      for (int jj = 0; jj < 4; ++jj) acc[q][jj] = 0.0f;
    const float* Db = Dg + (size_t)(b * 8 + i) * 16384;
    for (int kc = 0; kc < 128; kc += 32) {
#pragma unroll
      for (int q = 0; q < 4; ++q) {
        int idx = t + 256 * q;
        int r = idx >> 3, c4 = idx & 7;
        float4 v = *(const float4*)&Db[r * 128 + kc + c4 * 4];
        As[(c4 * 4 + 0) * 132 + r] = v.x;
        As[(c4 * 4 + 1) * 132 + r] = v.y;
        As[(c4 * 4 + 2) * 132 + r] = v.z;
        As[(c4 * 4 + 3) * 132 + r] = v.w;
      }
      __syncthreads();
#pragma unroll 4
      for (int c = 0; c < 32; ++c) {
        float4 a0 = *(const float4*)&As[c * 132 + ty * 8];
        float4 a1 = *(const float4*)&As[c * 132 + ty * 8 + 4];
        float4 bv = *(const float4*)&Ts[(kc + c) * 68 + tx * 4];
        float av[8] = {a0.x, a0.y, a0.z, a0.w, a1.x, a1.y, a1.z, a1.w};
        float bb[4] = {bv.x, bv.y, bv.z, bv.w};
#pragma unroll
        for (int q = 0; q < 8; ++q)
#pragma unroll
          for (int jj = 0; jj < 4; ++jj) acc[q][jj] = fmaf(av[q], bb[jj], acc[q][jj]);
      }
      __syncthreads();
    }
    // ---- store w_i to slab (not needed for i==7), accumulate pm/s2 ----
    if (i < 7) {
#pragma unroll
      for (int q = 0; q < 8; ++q) {
        float4 v = {acc[q][0], acc[q][1], acc[q][2], acc[q][3]};
        *(float4*)&slab[(size_t)(i * 128 + ty * 8 + q) * 64 + tx * 4] = v;
      }
    }
#pragma unroll
    for (int q = 0; q < 8; ++q) {
      float zv = zs[ty * 8 + q];
#pragma unroll
      for (int jj = 0; jj < 4; ++jj) {
        pmc[jj] = fmaf(acc[q][jj], zv, pmc[jj]);
        s2c[jj] = fmaf(acc[q][jj], acc[q][jj], s2c[jj]);
      }
    }
    __syncthreads();
  }
  // ---- reduce over ty and write outputs ----
#pragma unroll
  for (int jj = 0; jj < 4; ++jj) {
    As[t * 4 + jj] = pmc[jj];
    As[1024 + t * 4 + jj] = s2c[jj];
  }
  __syncthreads();
  if (t < 64) {
    int txr = t >> 2, jr = t & 3;
    float pm = 0.0f, s2 = 0.0f;
#pragma unroll
    for (int ty2 = 0; ty2 < 16; ++ty2) {
      pm += As[(ty2 * 16 + txr) * 4 + jr];
      s2 += As[1024 + (ty2 * 16 + txr) * 4 + jr];
    }
    int mg = mt * 64 + t;
    float a = tss[t * 5 + 2], bb = tss[t * 5 + 3], cc = tss[t * 5 + 4];
    float det = a * bb - cc * cc;
    float C = 2.0f * sqrtf(det) * rsqrtf(fmaxf(4.0f * det, 1e-5f));
    float t0 = kSqrt3 * sqrtf(1e-5f);
    float mat = (1.0f + t0) * __expf(-t0);
    float kd = C * mat * scale;
    out[b * kM + mg] = meanp[b] + pm;
    out[kB * kM + b * kM + mg] = kd - s2;
  }
}

extern "C" void kernel_launch(void* const* d_in, const int* in_sizes, int n_in,
                              void* d_out, int out_size, void* d_ws, size_t ws_size,
                              hipStream_t stream) {
  const float* xt = (const float*)d_in[0];
  const float* pt = (const float*)d_in[1];
  const float* xs = (const float*)d_in[2];
  const float* ps = (const float*)d_in[3];
  const float* y = (const float*)d_in[4];
  const float* var = (const float*)d_in[5];
  const float* meanp = (const float*)d_in[6];
  const float* sp = (const float*)d_in[7];
  float* out = (float*)d_out;
  float* ws = (float*)d_ws;
  if (ws_size < WS_FLOATS * sizeof(float)) return;

  float* A = ws + A_OFF;
  float* Dg = ws + D_OFF;
  float* zbuf = ws + Z_OFF;
  float* Kw = ws + K_OFF;

  build_A<<<(kB * kN * kN) / 256, 256, 0, stream>>>(xt, pt, var, sp, A);
  for (int p = 0; p < 8; ++p) {
    chol_panel<<<kB, 1024, 0, stream>>>(A, Dg, p);
    if (p < 7) {
      int nt = 7 - p;
      int npairs = nt * (nt + 1) / 2;
      chol_trail<<<dim3(npairs, kB), 1024, 2 * 128 * 129 * sizeof(float), stream>>>(A, Dg, p);
    }
  }
  solve_small<<<kB, 128, 0, stream>>>(A, Dg, y, meanp, zbuf, out);
  fused_solve<<<dim3(kM / 64, kB), 256, 0, stream>>>(A, Dg, xt, pt, xs, ps, sp, meanp,
                                                     zbuf, Kw, out);
}

// Round 4
// 1668.718 us; speedup vs baseline: 1.4214x; 1.4214x over previous
//
#include <hip/hip_runtime.h>
#include <math.h>

namespace {
constexpr int kB = 2;
constexpr int kN = 1024;
constexpr int kM = 16384;
constexpr float kSqrt3 = 1.7320508075688772f;

// workspace layout (bytes)
constexpr size_t A_BYTES = (size_t)kB * kN * kN * 4;
constexpr size_t DG_BYTES = (size_t)kB * 8 * 128 * 128 * 4;
constexpr size_t Z_BYTES = (size_t)kB * kN * 4;
constexpr size_t LH_BYTES = (size_t)kB * kN * kN * 2;
constexpr size_t DH_BYTES = (size_t)kB * 8 * 128 * 128 * 2;
constexpr size_t A_OFF = 0;
constexpr size_t DG_OFF = A_OFF + A_BYTES;
constexpr size_t Z_OFF = DG_OFF + DG_BYTES;
constexpr size_t LH_OFF = Z_OFF + Z_BYTES;
constexpr size_t LL_OFF = LH_OFF + LH_BYTES;
constexpr size_t DH_OFF = LL_OFF + LH_BYTES;
constexpr size_t DL_OFF = DH_OFF + DH_BYTES;
constexpr size_t WS_BYTES = DL_OFF + DH_BYTES;
}  // namespace

typedef __attribute__((ext_vector_type(8))) short short8v;
typedef __attribute__((ext_vector_type(4))) float floatx4;

__device__ __forceinline__ unsigned short b16rn(float x) {
  unsigned u = __float_as_uint(x);
  unsigned r = u + 0x7FFFu + ((u >> 16) & 1u);
  return (unsigned short)(r >> 16);
}
__device__ __forceinline__ float b16f(unsigned short h) {
  return __uint_as_float(((unsigned)h) << 16);
}

__device__ __forceinline__ float pair_kernel(
    float x0, float x1, float a1, float b1, float c1,
    float y0, float y1, float a2, float b2, float c2, float scale) {
  float det1 = a1 * b1 - c1 * c1;
  float det2 = a2 * b2 - c2 * c2;
  float s00 = a1 + a2, s11 = b1 + b2, s01 = c1 + c2;
  float sdet = s00 * s11 - s01 * s01;
  float d0 = x0 - y0, d1 = x1 - y1;
  float Q = 0.5f * (s11 * d0 * d0 - 2.0f * s01 * d0 * d1 + s00 * d1 * d1) / sdet;
  float C = 2.0f * sqrtf(sqrtf(det1)) * sqrtf(sqrtf(det2)) * rsqrtf(fmaxf(sdet, 1e-5f));
  float t = kSqrt3 * sqrtf(fmaxf(Q, 1e-5f));
  return (1.0f + t) * __expf(-t) * C * scale;
}

// ---------------- A = K_nn + diag(var) ----------------
__global__ __launch_bounds__(256) void build_A(
    const float* __restrict__ xt, const float* __restrict__ pt,
    const float* __restrict__ var, const float* __restrict__ sp,
    float* __restrict__ A) {
  int idx = blockIdx.x * 256 + threadIdx.x;
  int b = idx / (kN * kN);
  int r = (idx / kN) % kN;
  int c = idx % kN;
  float scale = __expf(sp[0]);
  const float* x1 = xt + ((size_t)b * kN + r) * 2;
  const float* p1 = pt + ((size_t)b * kN + r) * 3;
  const float* x2 = xt + ((size_t)b * kN + c) * 2;
  const float* p2 = pt + ((size_t)b * kN + c) * 3;
  float k = pair_kernel(x1[0], x1[1], p1[0], p1[1], p1[2],
                        x2[0], x2[1], p2[0], p2[1], p2[2], scale);
  if (r == c) k += var[b * kN + r];
  A[(size_t)idx] = k;
}

// Lt swizzled indexers for chol_panel
__device__ __forceinline__ int lt_idx4(int row, int f4) {
  return row * 128 + ((f4 ^ ((row >> 2) & 7)) << 2);
}
__device__ __forceinline__ int lt_idx(int row, int col) {
  return row * 128 + ((((col >> 2) ^ ((row >> 2) & 7)) << 2) | (col & 3));
}

// ---------------- Cholesky panel factor (128x128) + explicit inverse ----------------
__global__ __launch_bounds__(1024) void chol_panel(float* __restrict__ A,
                                                   float* __restrict__ Dg,
                                                   unsigned short* __restrict__ Dh,
                                                   unsigned short* __restrict__ Dl, int p) {
  __shared__ float Lt[128 * 128];
  __shared__ float Dt[128 * 132];
  __shared__ float Tt[3 * 32 * 33];
  int b = blockIdx.x;
  int t = threadIdx.x;
  float* Ab = A + (size_t)b * kN * kN;
  int r0 = p * 128;
  int tx = t & 31, ty = t >> 5;
  int i0 = ty * 4, j0 = tx * 4;
  bool lower = (ty >= tx);
  float acc[4][4];
  if (lower) {
#pragma unroll
    for (int q = 0; q < 4; ++q) {
      float4 v = *(const float4*)&Ab[(size_t)(r0 + i0 + q) * kN + r0 + j0];
      acc[q][0] = v.x; acc[q][1] = v.y; acc[q][2] = v.z; acc[q][3] = v.w;
    }
  }
  for (int kb = 0; kb < 32; ++kb) {
    int K0 = kb * 4;
    if (ty == kb && tx == kb) {
#pragma unroll
      for (int c = 0; c < 4; ++c) {
        float d = sqrtf(acc[c][c]);
        float inv = 1.0f / d;
        acc[c][c] = d;
#pragma unroll
        for (int i = c + 1; i < 4; ++i) acc[i][c] *= inv;
#pragma unroll
        for (int j = c + 1; j < 4; ++j)
#pragma unroll
          for (int i = j; i < 4; ++i) acc[i][j] -= acc[i][c] * acc[j][c];
      }
#pragma unroll
      for (int q = 0; q < 4; ++q) {
        float4 v;
        v.x = acc[q][0];
        v.y = (q >= 1) ? acc[q][1] : 0.0f;
        v.z = (q >= 2) ? acc[q][2] : 0.0f;
        v.w = (q >= 3) ? acc[q][3] : 0.0f;
        *(float4*)&Lt[lt_idx4(K0 + q, kb)] = v;
      }
    }
    __syncthreads();
    if (tx == kb && ty > kb) {
      float L4[4][4];
#pragma unroll
      for (int c = 0; c < 4; ++c)
#pragma unroll
        for (int j = 0; j <= c; ++j) L4[c][j] = Lt[lt_idx(K0 + c, K0 + j)];
#pragma unroll
      for (int c = 0; c < 4; ++c) {
#pragma unroll
        for (int j = 0; j < c; ++j) {
          float m = L4[c][j];
#pragma unroll
          for (int q = 0; q < 4; ++q) acc[q][c] -= m * acc[q][j];
        }
        float inv = 1.0f / L4[c][c];
#pragma unroll
        for (int q = 0; q < 4; ++q) acc[q][c] *= inv;
      }
#pragma unroll
      for (int q = 0; q < 4; ++q) {
        float4 v = {acc[q][0], acc[q][1], acc[q][2], acc[q][3]};
        *(float4*)&Lt[lt_idx4(i0 + q, kb)] = v;
      }
    }
    __syncthreads();
    if (tx > kb && lower) {
      float4 Ri[4], Rj[4];
#pragma unroll
      for (int q = 0; q < 4; ++q) Ri[q] = *(const float4*)&Lt[lt_idx4(i0 + q, kb)];
#pragma unroll
      for (int q = 0; q < 4; ++q) Rj[q] = *(const float4*)&Lt[lt_idx4(j0 + q, kb)];
#pragma unroll
      for (int qr = 0; qr < 4; ++qr)
#pragma unroll
        for (int qc = 0; qc < 4; ++qc)
          acc[qr][qc] -= Ri[qr].x * Rj[qc].x + Ri[qr].y * Rj[qc].y +
                         Ri[qr].z * Rj[qc].z + Ri[qr].w * Rj[qc].w;
    }
  }
  if (t < 128) {
    int q = t >> 5, c = t & 31, base = q * 32;
    for (int r = 0; r < 32; ++r) {
      float x;
      if (r < c) x = 0.0f;
      else if (r == c) x = 1.0f / Lt[lt_idx(base + r, base + r)];
      else {
        float s = 0.0f;
        for (int j = c; j < r; ++j)
          s += Lt[lt_idx(base + r, base + j)] * Dt[(base + j) * 132 + base + c];
        x = -s / Lt[lt_idx(base + r, base + r)];
      }
      Dt[(base + r) * 132 + base + c] = x;
    }
  }
  __syncthreads();
  {
    int r = t >> 5, cl = t & 31;
    for (int s = 1; s <= 3; ++s) {
      for (int blk = 0; blk < 4 - s; ++blk) {
        int J = blk, I = J + s;
        float sum = 0.0f;
        for (int K = J; K < I; ++K)
          for (int j = 0; j < 32; ++j)
            sum += Lt[lt_idx(I * 32 + r, K * 32 + j)] * Dt[(K * 32 + j) * 132 + J * 32 + cl];
        Tt[blk * (32 * 33) + r * 33 + cl] = sum;
      }
      __syncthreads();
      for (int blk = 0; blk < 4 - s; ++blk) {
        int J = blk, I = J + s;
        float sum = 0.0f;
        for (int j = 0; j < 32; ++j)
          sum += Dt[(I * 32 + r) * 132 + I * 32 + j] * Tt[blk * (32 * 33) + j * 33 + cl];
        Dt[(I * 32 + r) * 132 + J * 32 + cl] = -sum;
      }
      __syncthreads();
    }
  }
#pragma unroll
  for (int q = 0; q < 4; ++q) {
    int j = t + 1024 * q;
    int r = j >> 5, ch = j & 31;
    float4 v = *(const float4*)&Lt[lt_idx4(r, ch)];
    int c0 = ch * 4;
    v.x = (c0 + 0 <= r) ? v.x : 0.0f;
    v.y = (c0 + 1 <= r) ? v.y : 0.0f;
    v.z = (c0 + 2 <= r) ? v.z : 0.0f;
    v.w = (c0 + 3 <= r) ? v.w : 0.0f;
    *(float4*)&Ab[(size_t)(r0 + r) * kN + r0 + c0] = v;
  }
  float* Db = Dg + (size_t)(b * 8 + p) * 16384;
  unsigned short* Dhb = Dh + (size_t)(b * 8 + p) * 16384;
  unsigned short* Dlb = Dl + (size_t)(b * 8 + p) * 16384;
#pragma unroll
  for (int q = 0; q < 4; ++q) {
    int j = t + 1024 * q;
    int r = j >> 5, ch = j & 31;
    float4 v = *(const float4*)&Dt[r * 132 + ch * 4];
    int c0 = ch * 4;
    v.x = (c0 + 0 <= r) ? v.x : 0.0f;
    v.y = (c0 + 1 <= r) ? v.y : 0.0f;
    v.z = (c0 + 2 <= r) ? v.z : 0.0f;
    v.w = (c0 + 3 <= r) ? v.w : 0.0f;
    *(float4*)&Db[r * 128 + c0] = v;
    float vv[4] = {v.x, v.y, v.z, v.w};
#pragma unroll
    for (int e = 0; e < 4; ++e) {
      unsigned short h = b16rn(vv[e]);
      Dhb[r * 128 + c0 + e] = h;
      Dlb[r * 128 + c0 + e] = b16rn(vv[e] - b16f(h));
    }
  }
}

// ---------------- L21 = A21 * D_p^T (in place) + bf16 hi/lo split of -L ----------------
__global__ __launch_bounds__(256) void chol_trsm(float* __restrict__ A,
                                                 const float* __restrict__ Dg,
                                                 unsigned short* __restrict__ Lh,
                                                 unsigned short* __restrict__ Ll, int p) {
  __shared__ float At[128 * 129];
  __shared__ float Dt[128 * 129];
  int b = blockIdx.y, rb = blockIdx.x;
  int rs = (p + 1 + rb) * 128;
  float* Ab = A + (size_t)b * kN * kN;
  const float* Db = Dg + (size_t)(b * 8 + p) * 16384;
  int t = threadIdx.x;
  for (int q = 0; q < 64; ++q) {
    int li = t + 256 * q;
    int r = li >> 7, cc = li & 127;
    At[r * 129 + cc] = Ab[(size_t)(rs + r) * kN + p * 128 + cc];
    Dt[r * 129 + cc] = Db[r * 128 + cc];
  }
  __syncthreads();
  int tx = t & 15, ty = t >> 4;
  float acc[8][8] = {};
  for (int j = 0; j < 128; ++j) {
    float a[8], d[8];
#pragma unroll
    for (int q = 0; q < 8; ++q) a[q] = At[(ty * 8 + q) * 129 + j];
#pragma unroll
    for (int q = 0; q < 8; ++q) d[q] = Dt[(tx * 8 + q) * 129 + j];
#pragma unroll
    for (int qr = 0; qr < 8; ++qr)
#pragma unroll
      for (int qc = 0; qc < 8; ++qc) acc[qr][qc] = fmaf(a[qr], d[qc], acc[qr][qc]);
  }
#pragma unroll
  for (int qr = 0; qr < 8; ++qr)
#pragma unroll
    for (int qc = 0; qc < 8; ++qc) {
      float v = acc[qr][qc];
      Ab[(size_t)(rs + ty * 8 + qr) * kN + p * 128 + tx * 8 + qc] = v;
      size_t lo = ((size_t)b * kN + rs + ty * 8 + qr) * kN + p * 128 + tx * 8 + qc;
      float nv = -v;
      unsigned short h = b16rn(nv);
      Lh[lo] = h;
      Ll[lo] = b16rn(nv - b16f(h));
    }
}

// ---------------- A22 -= L21 * L21^T ----------------
__global__ __launch_bounds__(256) void chol_syrk(float* __restrict__ A, int p) {
  __shared__ float L1t[128 * 129];
  __shared__ float L2t[128 * 129];
  int b = blockIdx.y;
  int pid = blockIdx.x;
  int bi = 0;
  while ((bi + 1) * (bi + 2) / 2 <= pid) ++bi;
  int bj = pid - bi * (bi + 1) / 2;
  int rs1 = (p + 1 + bi) * 128, rs2 = (p + 1 + bj) * 128;
  float* Ab = A + (size_t)b * kN * kN;
  int t = threadIdx.x;
  for (int q = 0; q < 64; ++q) {
    int li = t + 256 * q;
    int r = li >> 7, cc = li & 127;
    L1t[r * 129 + cc] = Ab[(size_t)(rs1 + r) * kN + p * 128 + cc];
    L2t[r * 129 + cc] = Ab[(size_t)(rs2 + r) * kN + p * 128 + cc];
  }
  __syncthreads();
  int tx = t & 15, ty = t >> 4;
  float acc[8][8] = {};
  for (int j = 0; j < 128; ++j) {
    float a[8], d[8];
#pragma unroll
    for (int q = 0; q < 8; ++q) a[q] = L1t[(ty * 8 + q) * 129 + j];
#pragma unroll
    for (int q = 0; q < 8; ++q) d[q] = L2t[(tx * 8 + q) * 129 + j];
#pragma unroll
    for (int qr = 0; qr < 8; ++qr)
#pragma unroll
      for (int qc = 0; qc < 8; ++qc) acc[qr][qc] = fmaf(a[qr], d[qc], acc[qr][qc]);
  }
#pragma unroll
  for (int qr = 0; qr < 8; ++qr)
#pragma unroll
    for (int qc = 0; qc < 8; ++qc) {
      size_t o = (size_t)(rs1 + ty * 8 + qr) * kN + rs2 + tx * 8 + qc;
      Ab[o] -= acc[qr][qc];
    }
}

// ---------------- z = L^-1 (y - mean), nlml ----------------
__global__ __launch_bounds__(128) void solve_small(
    const float* __restrict__ A, const float* __restrict__ Dg,
    const float* __restrict__ y, const float* __restrict__ meanp,
    float* __restrict__ zbuf, float* __restrict__ out) {
  __shared__ __align__(16) float zs[1024];
  __shared__ float ts[128];
  __shared__ float red[128];
  int b = blockIdx.x, t = threadIdx.x;
  const float* Ab = A + (size_t)b * kN * kN;
  float mv = meanp[b];
  for (int q = t; q < 1024; q += 128) zs[q] = y[b * kN + q] - mv;
  __syncthreads();
  for (int i = 0; i < 8; ++i) {
    float acc = zs[i * 128 + t];
    const float* Lrow = Ab + (size_t)(i * 128 + t) * kN;
    for (int kk = 0; kk < i * 128; kk += 4) {
      float4 lv = *(const float4*)&Lrow[kk];
      float4 zv = *(const float4*)&zs[kk];
      acc -= lv.x * zv.x + lv.y * zv.y + lv.z * zv.z + lv.w * zv.w;
    }
    ts[t] = acc;
    __syncthreads();
    const float* Db = Dg + (size_t)(b * 8 + i) * 16384 + t * 128;
    float zv = 0.0f;
    for (int c = 0; c <= t; ++c) zv += Db[c] * ts[c];
    zs[i * 128 + t] = zv;
    __syncthreads();
  }
  float df = 0.0f, ld = 0.0f;
  for (int q = t; q < 1024; q += 128) {
    df += zs[q] * zs[q];
    ld += logf(Ab[(size_t)q * kN + q]);
  }
  red[t] = df;
  __syncthreads();
  for (int s = 64; s > 0; s >>= 1) {
    if (t < s) red[t] += red[t + s];
    __syncthreads();
  }
  float dfs = red[0];
  __syncthreads();
  red[t] = ld;
  __syncthreads();
  for (int s = 64; s > 0; s >>= 1) {
    if (t < s) red[t] += red[t + s];
    __syncthreads();
  }
  if (t == 0)
    out[2 * kB * kM + b] = 0.5f * dfs + red[0] + 0.5f * 1024.0f * logf(6.283185307179586f);
  for (int q = t; q < 1024; q += 128) zbuf[b * kN + q] = zs[q];
}

// ---------------- fused MFMA solve: K build + w = L^-1 K + outputs ----------------
// grid (kM/32, kB), 256 threads (4 waves). k-outer recurrence, accumulators resident.
__global__ __launch_bounds__(256, 2) void fused_mfma(
    const unsigned short* __restrict__ Lh, const unsigned short* __restrict__ Ll,
    const unsigned short* __restrict__ Dh, const unsigned short* __restrict__ Dl,
    const float* __restrict__ xt, const float* __restrict__ pt,
    const float* __restrict__ xs, const float* __restrict__ ps,
    const float* __restrict__ sp, const float* __restrict__ meanp,
    const float* __restrict__ zbuf, float* __restrict__ out) {
  __shared__ unsigned short Th[32 * 136];
  __shared__ unsigned short Tl[32 * 136];
  __shared__ float trp[128 * 6];
  __shared__ float tp[32 * 6];
  __shared__ float zs[128];
  __shared__ float red[32 * 16 * 2];
  int mt = blockIdx.x, b = blockIdx.y;
  int t = threadIdx.x;
  int lane = t & 63, wave = t >> 6;
  int lrow = lane & 15, kgrp = lane >> 4;
  float scale = __expf(sp[0]);
  if (t < 32) {
    int mg = mt * 32 + t;
    float x0 = xs[((size_t)b * kM + mg) * 2 + 0];
    float x1 = xs[((size_t)b * kM + mg) * 2 + 1];
    float a = ps[((size_t)b * kM + mg) * 3 + 0];
    float bb = ps[((size_t)b * kM + mg) * 3 + 1];
    float c = ps[((size_t)b * kM + mg) * 3 + 2];
    float det2 = a * bb - c * c;
    tp[t * 6 + 0] = x0; tp[t * 6 + 1] = x1; tp[t * 6 + 2] = a;
    tp[t * 6 + 3] = bb; tp[t * 6 + 4] = c; tp[t * 6 + 5] = sqrtf(sqrtf(det2));
  }
  floatx4 W[8][2][2];
#pragma unroll
  for (int i = 0; i < 8; ++i)
#pragma unroll
    for (int rf = 0; rf < 2; ++rf)
#pragma unroll
      for (int cf = 0; cf < 2; ++cf) W[i][rf][cf] = (floatx4){0.f, 0.f, 0.f, 0.f};
  float pma[2] = {0.f, 0.f}, s2a[2] = {0.f, 0.f};

#pragma unroll
  for (int k = 0; k < 8; ++k) {
    __syncthreads();  // prev iter plane reads done; tp visible (k=0)
    if (t < 128) {
      size_t n = (size_t)b * kN + k * 128 + t;
      float x0 = xt[n * 2 + 0];
      float x1 = xt[n * 2 + 1];
      float a = pt[n * 3 + 0];
      float bb = pt[n * 3 + 1];
      float c = pt[n * 3 + 2];
      float det1 = a * bb - c * c;
      trp[t * 6 + 0] = x0; trp[t * 6 + 1] = x1; trp[t * 6 + 2] = a;
      trp[t * 6 + 3] = bb; trp[t * 6 + 4] = c;
      trp[t * 6 + 5] = 2.0f * scale * sqrtf(sqrtf(det1));
      zs[t] = zbuf[n];
    }
    __syncthreads();
    // T = K_k + W[k]  -> planes (bf16 hi/lo)
#pragma unroll
    for (int rf = 0; rf < 2; ++rf) {
      int n0 = wave * 32 + rf * 16 + kgrp * 4;
      float nx0[4], nx1[4], na[4], nb[4], nc[4], nc1[4];
#pragma unroll
      for (int r = 0; r < 4; ++r) {
        int n = n0 + r;
        nx0[r] = trp[n * 6 + 0]; nx1[r] = trp[n * 6 + 1]; na[r] = trp[n * 6 + 2];
        nb[r] = trp[n * 6 + 3]; nc[r] = trp[n * 6 + 4]; nc1[r] = trp[n * 6 + 5];
      }
#pragma unroll
      for (int cf = 0; cf < 2; ++cf) {
        int m = cf * 16 + lrow;
        float mx0 = tp[m * 6 + 0], mx1 = tp[m * 6 + 1], ma = tp[m * 6 + 2];
        float mb = tp[m * 6 + 3], mc = tp[m * 6 + 4], mq = tp[m * 6 + 5];
        unsigned hw[2], lw[2];
#pragma unroll
        for (int r = 0; r < 4; ++r) {
          float s00 = na[r] + ma, s11 = nb[r] + mb, s01 = nc[r] + mc;
          float sdet = s00 * s11 - s01 * s01;
          float d0 = nx0[r] - mx0, d1 = nx1[r] - mx1;
          float quad = s11 * d0 * d0 - 2.0f * s01 * d0 * d1 + s00 * d1 * d1;
          float Q = 0.5f * quad / sdet;
          float tt = kSqrt3 * sqrtf(fmaxf(Q, 1e-5f));
          float Kv = (1.0f + tt) * __expf(-tt) * nc1[r] * mq * rsqrtf(fmaxf(sdet, 1e-5f));
          float T = Kv + W[k][rf][cf][r];
          unsigned short h = b16rn(T);
          unsigned short l = b16rn(T - b16f(h));
          if (r & 1) { hw[r >> 1] |= ((unsigned)h) << 16; lw[r >> 1] |= ((unsigned)l) << 16; }
          else { hw[r >> 1] = h; lw[r >> 1] = l; }
        }
        int off = m * 136 + n0;
        *(uint2*)&Th[off] = make_uint2(hw[0], hw[1]);
        *(uint2*)&Tl[off] = make_uint2(lw[0], lw[1]);
      }
    }
    __syncthreads();
    // wk = D_k * T   (MFMA, split bf16)
    floatx4 wk[2][2];
#pragma unroll
    for (int rf = 0; rf < 2; ++rf)
#pragma unroll
      for (int cf = 0; cf < 2; ++cf) wk[rf][cf] = (floatx4){0.f, 0.f, 0.f, 0.f};
    {
      const unsigned short* Dhb = Dh + (size_t)(b * 8 + k) * 16384;
      const unsigned short* Dlb = Dl + (size_t)(b * 8 + k) * 16384;
#pragma unroll
      for (int ks = 0; ks < 4; ++ks) {
        short8v bh[2], bl[2];
#pragma unroll
        for (int cf = 0; cf < 2; ++cf) {
          int boff = (cf * 16 + lrow) * 136 + ks * 32 + kgrp * 8;
          bh[cf] = *(const short8v*)&Th[boff];
          bl[cf] = *(const short8v*)&Tl[boff];
        }
#pragma unroll
        for (int rf = 0; rf < 2; ++rf) {
          size_t aoff = (size_t)(wave * 32 + rf * 16 + lrow) * 128 + ks * 32 + kgrp * 8;
          short8v ah = *(const short8v*)&Dhb[aoff];
          short8v al = *(const short8v*)&Dlb[aoff];
#pragma unroll
          for (int cf = 0; cf < 2; ++cf) {
            wk[rf][cf] = __builtin_amdgcn_mfma_f32_16x16x32_bf16(ah, bh[cf], wk[rf][cf], 0, 0, 0);
            wk[rf][cf] = __builtin_amdgcn_mfma_f32_16x16x32_bf16(ah, bl[cf], wk[rf][cf], 0, 0, 0);
            wk[rf][cf] = __builtin_amdgcn_mfma_f32_16x16x32_bf16(al, bh[cf], wk[rf][cf], 0, 0, 0);
          }
        }
      }
    }
    __syncthreads();
    // store w_k planes (overwrite T), accumulate pm/s2
#pragma unroll
    for (int rf = 0; rf < 2; ++rf) {
      int n0 = wave * 32 + rf * 16 + kgrp * 4;
#pragma unroll
      for (int cf = 0; cf < 2; ++cf) {
        int m = cf * 16 + lrow;
        unsigned hw[2], lw[2];
#pragma unroll
        for (int r = 0; r < 4; ++r) {
          float wv = wk[rf][cf][r];
          unsigned short h = b16rn(wv);
          unsigned short l = b16rn(wv - b16f(h));
          if (r & 1) { hw[r >> 1] |= ((unsigned)h) << 16; lw[r >> 1] |= ((unsigned)l) << 16; }
          else { hw[r >> 1] = h; lw[r >> 1] = l; }
          pma[cf] = fmaf(wv, zs[n0 + r], pma[cf]);
          s2a[cf] = fmaf(wv, wv, s2a[cf]);
        }
        int off = m * 136 + n0;
        *(uint2*)&Th[off] = make_uint2(hw[0], hw[1]);
        *(uint2*)&Tl[off] = make_uint2(lw[0], lw[1]);
      }
    }
    __syncthreads();
    // W[i] += (-L_ik) * w_k for i > k  (MFMA, split bf16)
#pragma unroll
    for (int ks = 0; ks < 4; ++ks) {
      short8v bh[2], bl[2];
#pragma unroll
      for (int cf = 0; cf < 2; ++cf) {
        int boff = (cf * 16 + lrow) * 136 + ks * 32 + kgrp * 8;
        bh[cf] = *(const short8v*)&Th[boff];
        bl[cf] = *(const short8v*)&Tl[boff];
      }
#pragma unroll
      for (int i = k + 1; i < 8; ++i) {
#pragma unroll
        for (int rf = 0; rf < 2; ++rf) {
          size_t ro = (size_t)b * kN + i * 128 + wave * 32 + rf * 16 + lrow;
          size_t aoff = ro * kN + k * 128 + ks * 32 + kgrp * 8;
          short8v ah = *(const short8v*)&Lh[aoff];
          short8v al = *(const short8v*)&Ll[aoff];
#pragma unroll
          for (int cf = 0; cf < 2; ++cf) {
            W[i][rf][cf] = __builtin_amdgcn_mfma_f32_16x16x32_bf16(ah, bh[cf], W[i][rf][cf], 0, 0, 0);
            W[i][rf][cf] = __builtin_amdgcn_mfma_f32_16x16x32_bf16(ah, bl[cf], W[i][rf][cf], 0, 0, 0);
            W[i][rf][cf] = __builtin_amdgcn_mfma_f32_16x16x32_bf16(al, bh[cf], W[i][rf][cf], 0, 0, 0);
          }
        }
      }
    }
  }
  __syncthreads();
#pragma unroll
  for (int cf = 0; cf < 2; ++cf) {
    int m = cf * 16 + lrow;
    red[m * 16 + wave * 4 + kgrp] = pma[cf];
    red[512 + m * 16 + wave * 4 + kgrp] = s2a[cf];
  }
  __syncthreads();
  if (t < 32) {
    float pm = 0.f, s2 = 0.f;
#pragma unroll
    for (int j = 0; j < 16; ++j) {
      pm += red[t * 16 + j];
      s2 += red[512 + t * 16 + j];
    }
    int mg = mt * 32 + t;
    float a = tp[t * 6 + 2], bb = tp[t * 6 + 3], c = tp[t * 6 + 4];
    float det = a * bb - c * c;
    float C = 2.0f * sqrtf(det) * rsqrtf(fmaxf(4.0f * det, 1e-5f));
    float t0 = kSqrt3 * sqrtf(1e-5f);
    float mat = (1.0f + t0) * __expf(-t0);
    float kd = C * mat * scale;
    out[b * kM + mg] = meanp[b] + pm;
    out[kB * kM + b * kM + mg] = kd - s2;
  }
}

extern "C" void kernel_launch(void* const* d_in, const int* in_sizes, int n_in,
                              void* d_out, int out_size, void* d_ws, size_t ws_size,
                              hipStream_t stream) {
  const float* xt = (const float*)d_in[0];
  const float* pt = (const float*)d_in[1];
  const float* xs = (const float*)d_in[2];
  const float* ps = (const float*)d_in[3];
  const float* y = (const float*)d_in[4];
  const float* var = (const float*)d_in[5];
  const float* meanp = (const float*)d_in[6];
  const float* sp = (const float*)d_in[7];
  float* out = (float*)d_out;
  char* ws = (char*)d_ws;
  if (ws_size < WS_BYTES) return;

  float* A = (float*)(ws + A_OFF);
  float* Dg = (float*)(ws + DG_OFF);
  float* zbuf = (float*)(ws + Z_OFF);
  unsigned short* Lh = (unsigned short*)(ws + LH_OFF);
  unsigned short* Ll = (unsigned short*)(ws + LL_OFF);
  unsigned short* Dh = (unsigned short*)(ws + DH_OFF);
  unsigned short* Dl = (unsigned short*)(ws + DL_OFF);

  build_A<<<(kB * kN * kN) / 256, 256, 0, stream>>>(xt, pt, var, sp, A);
  for (int p = 0; p < 8; ++p) {
    chol_panel<<<kB, 1024, 0, stream>>>(A, Dg, Dh, Dl, p);
    if (p < 7) {
      int nt = 7 - p;
      chol_trsm<<<dim3(nt, kB), 256, 0, stream>>>(A, Dg, Lh, Ll, p);
      chol_syrk<<<dim3(nt * (nt + 1) / 2, kB), 256, 0, stream>>>(A, p);
    }
  }
  solve_small<<<kB, 128, 0, stream>>>(A, Dg, y, meanp, zbuf, out);
  fused_mfma<<<dim3(kM / 32, kB), 256, 0, stream>>>(Lh, Ll, Dh, Dl, xt, pt, xs, ps,
                                                    sp, meanp, zbuf, out);
}